// Round 11
// baseline (2644.689 us; speedup 1.0000x reference)
//
#include <hip/hip_runtime.h>
#include <math.h>

#define N_NODES 16384
#define N_EDGES 524288
#define D_FEAT  128
#define BATCH   4
#define NPTS    4096   // points per cloud
#define KSEL    2048   // selected per cloud
#define MSEL    (BATCH*KSEL)  // 8192
#define NCHUNK  32     // 128 points per chunk
#define CH_SH   7      // log2(128)

// ---------------------------------------------------------------------------
// Grid-pruned FPS. One block per cloud, 256 threads (4 waves).
//  - One-time: cloud bbox -> 9-bit Morton counting sort (512 cells) ->
//    32 chunks of 128 spatially-coherent points, per-chunk bbox.
//  - Per step: chunk skip test (bound-to-bbox vs cached chunk max, with
//    conservative 1e-5 margin -> provably exact: skipped chunks cannot
//    change any dist), dirty chunks processed round-robin across waves,
//    parity double-buffered chunk candidates -> ONE barrier per step,
//    global argmax over 32 cached candidates computed redundantly per wave.
//  - Exactness: same __fsub/__fmul/__fadd/fminf arithmetic; tie-break on
//    ORIGINAL index via packed u64 (val:32 | 4095-orig:12 | sorted:12).
// R10 bug fixed here: hist[256..511] was never zeroed (256 threads vs
// 'if (tid < 512)') -> garbage Morton counts -> corrupted sort. Now all
// 512 bins are zeroed explicitly.
// Fallback if this regresses: R9 kernel (fps 1107us, total 1260us).
// ---------------------------------------------------------------------------

__device__ __forceinline__ unsigned long long dpp_max_step(unsigned long long p,
                                                           unsigned int slo,
                                                           unsigned int shi)
{
    unsigned long long s = (((unsigned long long)shi) << 32) | slo;
    return (s > p) ? s : p;
}

__device__ __forceinline__ unsigned long long wave_max_u64(unsigned long long p)
{
    unsigned int lo, hi, slo, shi;
#define DSTEP(CTRL) \
    lo = (unsigned int)p; hi = (unsigned int)(p >> 32); \
    slo = __builtin_amdgcn_update_dpp(0, (int)lo, CTRL, 0xf, 0xf, true); \
    shi = __builtin_amdgcn_update_dpp(0, (int)hi, CTRL, 0xf, 0xf, true); \
    p = dpp_max_step(p, slo, shi);
    DSTEP(0x111) DSTEP(0x112) DSTEP(0x114) DSTEP(0x118) DSTEP(0x142) DSTEP(0x143)
#undef DSTEP
    return p;
}

__device__ __forceinline__ float wave_min_f32(float v)
{
#define MSTEP(CTRL) { int r_ = __builtin_amdgcn_update_dpp(__float_as_int(v), \
        __float_as_int(v), CTRL, 0xf, 0xf, false); v = fminf(v, __int_as_float(r_)); }
    MSTEP(0x111) MSTEP(0x112) MSTEP(0x114) MSTEP(0x118) MSTEP(0x142) MSTEP(0x143)
#undef MSTEP
    return v;
}
__device__ __forceinline__ float wave_max_f32(float v)
{
#define MSTEP(CTRL) { int r_ = __builtin_amdgcn_update_dpp(__float_as_int(v), \
        __float_as_int(v), CTRL, 0xf, 0xf, false); v = fmaxf(v, __int_as_float(r_)); }
    MSTEP(0x111) MSTEP(0x112) MSTEP(0x114) MSTEP(0x118) MSTEP(0x142) MSTEP(0x143)
#undef MSTEP
    return v;
}

__device__ __forceinline__ int spread3(int c)
{
    return (c & 1) | ((c & 2) << 2) | ((c & 4) << 4);  // bits 0,3,6
}

__launch_bounds__(256, 1)
__global__ void fps_kernel(const float* __restrict__ pos,
                           int* __restrict__ fp_int,
                           int* __restrict__ inv,
                           float* __restrict__ out_subx,
                           float* __restrict__ out_fp)
{
    __shared__ float ssx[NPTS], ssy[NPTS], ssz[NPTS];   // Morton-sorted coords
    __shared__ float sdist[NPTS];                       // min sq-dist (sorted order)
    __shared__ int   sperm[NPTS];                       // sorted pos -> orig idx
    __shared__ int   sel_o[KSEL], sel_s[KSEL];          // selections (orig, sorted)
    __shared__ float bbl[3][NCHUNK], bbh[3][NCHUNK];    // chunk bboxes
    __shared__ unsigned cand_hi[2][NCHUNK], cand_lo[2][NCHUNK];
    __shared__ int   hist[512];
    __shared__ int   part[256];
    __shared__ float cb[8];                             // cloud bbox
    __shared__ int   s0pos;

    const int b    = blockIdx.x;
    const int tid  = threadIdx.x;
    const int lane = tid & 63;
    const int wv   = tid >> 6;
    const float* gp = pos + (size_t)b * NPTS * 3;

    // ---- phase 1: cloud bbox (sdist used as scratch) ----
    {
        float mnx = 1e30f, mny = 1e30f, mnz = 1e30f;
        float mxx = -1e30f, mxy = -1e30f, mxz = -1e30f;
        for (int i = tid; i < NPTS; i += 256) {
            float x = gp[3*i+0], y = gp[3*i+1], z = gp[3*i+2];
            mnx = fminf(mnx, x); mny = fminf(mny, y); mnz = fminf(mnz, z);
            mxx = fmaxf(mxx, x); mxy = fmaxf(mxy, y); mxz = fmaxf(mxz, z);
        }
        sdist[tid]        = mnx; sdist[256 + tid]  = mny; sdist[512 + tid]  = mnz;
        sdist[768 + tid]  = mxx; sdist[1024 + tid] = mxy; sdist[1280 + tid] = mxz;
        hist[tid]       = 0;   // R10 bug fix: zero ALL 512 bins
        hist[tid + 256] = 0;
        __syncthreads();
        if (tid < 6) {
            int base = tid * 256;
            float v = sdist[base];
            for (int i = 1; i < 256; ++i) {
                float u = sdist[base + i];
                v = (tid < 3) ? fminf(v, u) : fmaxf(v, u);
            }
            cb[tid] = v;
        }
        __syncthreads();
    }
    float lox = cb[0], loy = cb[1], loz = cb[2];
    float ex = cb[3] - lox, ey = cb[4] - loy, ez = cb[5] - loz;
    float scx = (ex > 0.0f) ? 7.999f / ex : 0.0f;
    float scy = (ey > 0.0f) ? 7.999f / ey : 0.0f;
    float scz = (ez > 0.0f) ? 7.999f / ez : 0.0f;

    // ---- phase 2: Morton histogram ----
    for (int i = tid; i < NPTS; i += 256) {
        float x = gp[3*i+0], y = gp[3*i+1], z = gp[3*i+2];
        int cx = min(7, max(0, (int)((x - lox) * scx)));
        int cy = min(7, max(0, (int)((y - loy) * scy)));
        int cz = min(7, max(0, (int)((z - loz) * scz)));
        int code = (spread3(cx) << 2) | (spread3(cy) << 1) | spread3(cz);
        atomicAdd(&hist[code], 1);
    }
    __syncthreads();
    // ---- phase 3: exclusive scan of 512 bins (2 per thread) ----
    {
        int h0 = hist[2*tid], h1 = hist[2*tid+1];
        part[tid] = h0 + h1;
        __syncthreads();
        for (int off = 1; off < 256; off <<= 1) {
            int v = part[tid];
            int a = (tid >= off) ? part[tid - off] : 0;
            __syncthreads();
            part[tid] = v + a;
            __syncthreads();
        }
        int excl = (tid == 0) ? 0 : part[tid - 1];
        hist[2*tid]   = excl;        // hist becomes the scatter cursor
        hist[2*tid+1] = excl + h0;
        __syncthreads();
    }
    // ---- phase 4: scatter into sorted arrays ----
    for (int i = tid; i < NPTS; i += 256) {
        float x = gp[3*i+0], y = gp[3*i+1], z = gp[3*i+2];
        int cx = min(7, max(0, (int)((x - lox) * scx)));
        int cy = min(7, max(0, (int)((y - loy) * scy)));
        int cz = min(7, max(0, (int)((z - loz) * scz)));
        int code = (spread3(cx) << 2) | (spread3(cy) << 1) | spread3(cz);
        int p = atomicAdd(&hist[code], 1);
        ssx[p] = x; ssy[p] = y; ssz[p] = z; sperm[p] = i;
        if (i == 0) s0pos = p;
    }
    __syncthreads();
    // ---- phase 5: per-chunk bbox + state init ----
    for (int c = wv; c < NCHUNK; c += 4) {
        int j0 = (c << CH_SH) + lane, j1 = j0 + 64;
        float ax = ssx[j0], bx = ssx[j1];
        float ay = ssy[j0], by = ssy[j1];
        float az = ssz[j0], bz = ssz[j1];
        float mnx = wave_min_f32(fminf(ax, bx));
        float mxx = wave_max_f32(fmaxf(ax, bx));
        float mny = wave_min_f32(fminf(ay, by));
        float mxy = wave_max_f32(fmaxf(ay, by));
        float mnz = wave_min_f32(fminf(az, bz));
        float mxz = wave_max_f32(fmaxf(az, bz));
        if (lane == 63) {
            bbl[0][c] = mnx; bbh[0][c] = mxx;
            bbl[1][c] = mny; bbh[1][c] = mxy;
            bbl[2][c] = mnz; bbh[2][c] = mxz;
        }
    }
    for (int i = tid; i < NPTS; i += 256) sdist[i] = 1e10f;
    if (tid < NCHUNK) {
        cand_hi[1][tid] = 0x7F800000u;  // +inf -> everything dirty at t=0
        cand_lo[1][tid] = 0u;
    }
    __syncthreads();

    // ---- main loop ----
    int cur_orig = 0;
    int cur_sorted = s0pos;
    float qx = ssx[cur_sorted], qy = ssy[cur_sorted], qz = ssz[cur_sorted];

    for (int t = 0; t < KSEL; ++t) {
        if (tid == 0) { sel_o[t] = cur_orig; sel_s[t] = cur_sorted; }
        int par = t & 1;

        // (A) skip test — all waves redundantly (identical inputs)
        int c0 = lane & 31;
        float ux = fmaxf(0.0f, fmaxf(bbl[0][c0] - qx, qx - bbh[0][c0]));
        float uy = fmaxf(0.0f, fmaxf(bbl[1][c0] - qy, qy - bbh[1][c0]));
        float uz = fmaxf(0.0f, fmaxf(bbl[2][c0] - qz, qz - bbh[2][c0]));
        float bnd = __fadd_rn(__fadd_rn(__fmul_rn(ux,ux), __fmul_rn(uy,uy)),
                              __fmul_rn(uz,uz)) * 0.99999f;  // conservative
        float cmax = __int_as_float((int)cand_hi[par ^ 1][c0]);
        bool dirty = (lane < 32) && !(bnd > cmax);
        unsigned m32 = (unsigned)__ballot(dirty);

        // carry over non-dirty candidates (redundant same-value writes)
        if (lane < 32 && !((m32 >> lane) & 1)) {
            cand_hi[par][lane] = cand_hi[par ^ 1][lane];
            cand_lo[par][lane] = cand_lo[par ^ 1][lane];
        }

        // (B) update dirty chunks, round-robin over waves
        {
            unsigned m = m32; int r = 0;
            while (m) {
                int c = __ffs(m) - 1; m &= m - 1;
                if ((r & 3) == wv) {
                    int j0 = (c << CH_SH) + lane, j1 = j0 + 64;
                    float ax = ssx[j0], ay = ssy[j0], az = ssz[j0];
                    float bx = ssx[j1], by = ssy[j1], bz = ssz[j1];
                    float d0 = sdist[j0], d1 = sdist[j1];
                    int   o0 = sperm[j0], o1 = sperm[j1];
                    float dx0 = __fsub_rn(ax, qx), dy0 = __fsub_rn(ay, qy), dz0 = __fsub_rn(az, qz);
                    float dd0 = __fadd_rn(__fadd_rn(__fmul_rn(dx0,dx0), __fmul_rn(dy0,dy0)),
                                          __fmul_rn(dz0,dz0));
                    float dx1 = __fsub_rn(bx, qx), dy1 = __fsub_rn(by, qy), dz1 = __fsub_rn(bz, qz);
                    float dd1 = __fadd_rn(__fadd_rn(__fmul_rn(dx1,dx1), __fmul_rn(dy1,dy1)),
                                          __fmul_rn(dz1,dz1));
                    float n0 = fminf(d0, dd0); sdist[j0] = n0;
                    float n1 = fminf(d1, dd1); sdist[j1] = n1;
                    unsigned long long p0 =
                        (((unsigned long long)__float_as_uint(n0)) << 32) |
                        (((unsigned)(4095 - o0)) << 20) | (((unsigned)j0) << 8);
                    unsigned long long p1 =
                        (((unsigned long long)__float_as_uint(n1)) << 32) |
                        (((unsigned)(4095 - o1)) << 20) | (((unsigned)j1) << 8);
                    unsigned long long p = (p1 > p0) ? p1 : p0;
                    p = wave_max_u64(p);
                    if (lane == 63) {
                        cand_hi[par][c] = (unsigned)(p >> 32);
                        cand_lo[par][c] = (unsigned)p;
                    }
                }
                ++r;
            }
        }

        // (C) the single barrier per step
        __syncthreads();

        // (D) global argmax over 32 candidates — redundantly in every wave
        {
            unsigned chi = cand_hi[par][c0];
            unsigned clo = cand_lo[par][c0];
            unsigned long long p = (((unsigned long long)chi) << 32) | clo;
            p = wave_max_u64(p);
            unsigned wlo = (unsigned)__builtin_amdgcn_readlane((int)(unsigned)p, 63);
            cur_sorted = (int)((wlo >> 8) & 0xFFFu);
            cur_orig   = 4095 - (int)((wlo >> 20) & 0xFFFu);
            qx = ssx[cur_sorted]; qy = ssy[cur_sorted]; qz = ssz[cur_sorted];
        }
    }
    __syncthreads();

    // epilogue
    for (int t = tid; t < KSEL; t += 256) {
        int so = sel_s[t];
        int g  = b * NPTS + sel_o[t];
        int m  = b * KSEL + t;
        fp_int[m] = g;
        inv[g] = m;
        out_fp[m] = (float)g;
        out_subx[m * 3 + 0] = ssx[so];
        out_subx[m * 3 + 1] = ssy[so];
        out_subx[m * 3 + 2] = ssz[so];
    }
}

// ---------------- in-degree histogram + inv init --------------------------
__global__ void deg_kernel(const int* __restrict__ dst, int* __restrict__ deg,
                           int* __restrict__ inv)
{
    int e = blockIdx.x * blockDim.x + threadIdx.x;
    if (e < N_NODES) inv[e] = -1;
    if (e < N_EDGES) atomicAdd(&deg[dst[e]], 1);
}

// ---------------- exclusive scan over deg -> row_ptr (+ cursor copy) ------
__global__ void scan_kernel(const int* __restrict__ deg, int* __restrict__ row_ptr,
                            int* __restrict__ row_ptr2)
{
    __shared__ int part[1024];
    int tid = threadIdx.x;
    int base = tid * 16;
    int local[16];
    int s = 0;
#pragma unroll
    for (int j = 0; j < 16; ++j) { local[j] = s; s += deg[base + j]; }
    part[tid] = s;
    __syncthreads();
    for (int off = 1; off < 1024; off <<= 1) {
        int v = part[tid];
        int add = (tid >= off) ? part[tid - off] : 0;
        __syncthreads();
        part[tid] = v + add;
        __syncthreads();
    }
    int prefix = (tid == 0) ? 0 : part[tid - 1];
#pragma unroll
    for (int j = 0; j < 16; ++j) {
        int v = prefix + local[j];
        row_ptr[base + j]  = v;
        row_ptr2[base + j] = v;
    }
    if (tid == 1023) row_ptr[N_NODES] = part[1023];
}

// ---------------- CSR scatter (row_ptr2 doubles as cursor) ----------------
__global__ void scatter_kernel(const int* __restrict__ src, const int* __restrict__ dst,
                               int* __restrict__ row_ptr2, int* __restrict__ col)
{
    int e = blockIdx.x * blockDim.x + threadIdx.x;
    if (e < N_EDGES) {
        int r = atomicAdd(&row_ptr2[dst[e]], 1);
        col[r] = src[e];
    }
}

// ---------------- fused agg (blocks 0..2047) + edge (blocks 2048..4095) ---
__global__ void agg_edge_kernel(const float* __restrict__ feat,
                                const int* __restrict__ fp_int,
                                const int* __restrict__ row_ptr,
                                const int* __restrict__ col,
                                const int* __restrict__ deg,
                                float* __restrict__ out_subfeat,
                                const int* __restrict__ src,
                                const int* __restrict__ dst,
                                const int* __restrict__ inv,
                                const float* __restrict__ subx,
                                float* __restrict__ outd,
                                float* __restrict__ outw,
                                float* __restrict__ outm)
{
    if (blockIdx.x < 2048) {
        int wid  = (blockIdx.x * blockDim.x + threadIdx.x) >> 6;
        int lane = threadIdx.x & 63;
        int v  = fp_int[wid];
        int s0 = row_ptr[v];
        int s1 = row_ptr[v + 1];
        float a0 = 0.0f, a1 = 0.0f, b0 = 0.0f, b1 = 0.0f;
        int e = s0;
        for (; e + 1 < s1; e += 2) {
            int sA = col[e];
            int sB = col[e + 1];
            float2 vA = ((const float2*)(feat + (size_t)sA * D_FEAT))[lane];
            float2 vB = ((const float2*)(feat + (size_t)sB * D_FEAT))[lane];
            a0 += vA.x; a1 += vA.y;
            b0 += vB.x; b1 += vB.y;
        }
        if (e < s1) {
            int sA = col[e];
            float2 vA = ((const float2*)(feat + (size_t)sA * D_FEAT))[lane];
            a0 += vA.x; a1 += vA.y;
        }
        a0 += b0; a1 += b1;
        float dv = fmaxf((float)deg[v], 1.0f);
        float* o = out_subfeat + (size_t)wid * D_FEAT + lane * 2;
        o[0] = a0 / dv;
        o[1] = a1 / dv;
    } else {
        int e = (blockIdx.x - 2048) * blockDim.x + threadIdx.x;
        int ls = inv[src[e]];
        int ld = inv[dst[e]];
        bool mk = (ls >= 0) && (ld >= 0);
        float dx = 0.0f, dy = 0.0f, dz = 0.0f;
        if (mk) {
            dx = __fsub_rn(subx[ld * 3 + 0], subx[ls * 3 + 0]);
            dy = __fsub_rn(subx[ld * 3 + 1], subx[ls * 3 + 1]);
            dz = __fsub_rn(subx[ld * 3 + 2], subx[ls * 3 + 2]);
        }
        float w = sqrtf(__fadd_rn(__fadd_rn(__fmul_rn(dx, dx), __fmul_rn(dy, dy)),
                                  __fmul_rn(dz, dz)));
        outd[e * 3 + 0] = dx;
        outd[e * 3 + 1] = dy;
        outd[e * 3 + 2] = dz;
        outw[e] = w;
        outm[e] = mk ? 1.0f : 0.0f;
    }
}

// ---------------- launch ---------------------------------------------------
extern "C" void kernel_launch(void* const* d_in, const int* in_sizes, int n_in,
                              void* d_out, int out_size, void* d_ws, size_t ws_size,
                              hipStream_t stream)
{
    const float* pos  = (const float*)d_in[0];   // [16384,3]
    const float* feat = (const float*)d_in[1];   // [16384,128]
    const int*   src  = (const int*)d_in[2];     // [524288]
    const int*   dst  = (const int*)d_in[3];     // [524288]

    float* out = (float*)d_out;
    float* out_subx    = out;                                 // [8192,3]
    float* out_subfeat = out_subx + (size_t)MSEL * 3;         // [8192,128]
    float* out_d       = out_subfeat + (size_t)MSEL * D_FEAT; // [524288,3]
    float* out_w       = out_d + (size_t)N_EDGES * 3;         // [524288]
    float* out_m       = out_w + (size_t)N_EDGES;             // [524288]
    float* out_fp      = out_m + (size_t)N_EDGES;             // [8192]

    int* fp_int   = (int*)d_ws;               // 8192
    int* inv      = fp_int + MSEL;            // 16384
    int* deg      = inv + N_NODES;            // 16384
    int* row_ptr  = deg + N_NODES;            // 16385
    int* row_ptr2 = row_ptr + (N_NODES + 1);  // 16385
    int* col      = row_ptr2 + (N_NODES + 1); // 524288

    (void)hipMemsetAsync(deg, 0, (size_t)N_NODES * 4, stream);

    deg_kernel<<<N_EDGES / 256, 256, 0, stream>>>(dst, deg, inv);
    scan_kernel<<<1, 1024, 0, stream>>>(deg, row_ptr, row_ptr2);
    scatter_kernel<<<N_EDGES / 256, 256, 0, stream>>>(src, dst, row_ptr2, col);

    fps_kernel<<<BATCH, 256, 0, stream>>>(pos, fp_int, inv, out_subx, out_fp);

    agg_edge_kernel<<<4096, 256, 0, stream>>>(feat, fp_int, row_ptr, col, deg,
                                              out_subfeat, src, dst, inv, out_subx,
                                              out_d, out_w, out_m);
}

// Round 12
// 1261.086 us; speedup vs baseline: 2.0972x; 2.0972x over previous
//
#include <hip/hip_runtime.h>
#include <math.h>

#define N_NODES 16384
#define N_EDGES 524288
#define D_FEAT  128
#define BATCH   4
#define NPTS    4096   // points per cloud
#define KSEL    2048   // selected per cloud
#define MSEL    (BATCH*KSEL)  // 8192

#define X16(F) F(0) F(1) F(2) F(3) F(4) F(5) F(6) F(7) \
               F(8) F(9) F(10) F(11) F(12) F(13) F(14) F(15)

// ---------------------------------------------------------------------------
// FPS: byte-identical hot loop to the measured-1105/1107us R2/R7/R9 variant.
// Regression log (do not reintroduce without counter evidence):
//   pk-asm packed math +100us; tournament-tree argmax +20-60us; two-phase
//   f32/u32 reduce +160us; float4-interleaved query +worse; fusing deg
//   blocks into this dispatch +60us AND races on inv (R8); Morton-chunk
//   spatial pruning 2.3x SLOWER (R11: dirty fraction ~0.88 on Gaussian
//   clouds — only 12% VALU-work cut — plus serialized per-chunk DPP
//   reduces tripled step latency, LDS conflicts 1938 -> 15k).
// deg/scan/scatter MUST complete before fps launches (inv ordering).
// ---------------------------------------------------------------------------

__device__ __forceinline__ unsigned long long dpp_max_step(unsigned long long p,
                                                           unsigned int slo,
                                                           unsigned int shi)
{
    unsigned long long s = (((unsigned long long)shi) << 32) | slo;
    return (s > p) ? s : p;
}

__launch_bounds__(256, 1)
__global__ void fps_kernel(const float* __restrict__ pos,
                           int* __restrict__ fp_int,
                           int* __restrict__ inv,
                           float* __restrict__ out_subx,
                           float* __restrict__ out_fp)
{
    __shared__ float sx[NPTS];
    __shared__ float sy[NPTS];
    __shared__ float sz[NPTS];
    __shared__ int   sel[KSEL];
    __shared__ unsigned long long pwv[2][4];

    const int b   = blockIdx.x;
    const int tid = threadIdx.x;

    const float* gp = pos + (size_t)b * NPTS * 3;
    for (int i = tid; i < NPTS; i += 256) {
        sx[i] = gp[3 * i + 0];
        sy[i] = gp[3 * i + 1];
        sz[i] = gp[3 * i + 2];
    }
    __syncthreads();

#define DECL(J) float x##J, y##J, z##J, d##J;
    X16(DECL)
#undef DECL
#define LOAD(J) { int li = (J)*256 + tid; x##J = sx[li]; y##J = sy[li]; z##J = sz[li]; d##J = 1e10f; }
    X16(LOAD)
#undef LOAD

    int cur = 0;
    for (int t = 0; t < KSEL; ++t) {
        if (tid == 0) sel[t] = cur;
        float qx = sx[cur];
        float qy = sy[cur];
        float qz = sz[cur];

        float bv = -1.0f;
        int   bi = 0x7fffffff;
        // exact reference arithmetic: (dx*dx + dy*dy) + dz*dz, no fma; fminf;
        // strict > keeps smallest index on ties (j ascending = idx ascending)
#define UPD(J) { \
        float dx = __fsub_rn(x##J, qx); \
        float dy = __fsub_rn(y##J, qy); \
        float dz = __fsub_rn(z##J, qz); \
        float dd = __fadd_rn(__fadd_rn(__fmul_rn(dx, dx), __fmul_rn(dy, dy)), \
                             __fmul_rn(dz, dz)); \
        d##J = fminf(d##J, dd); \
        if (d##J > bv) { bv = d##J; bi = (J)*256 + tid; } }
        X16(UPD)
#undef UPD

        // pack: nonneg float bits are order-preserving as unsigned;
        // tie -> larger ~idx -> smaller idx (matches argmax first-occurrence)
        unsigned long long p =
            (((unsigned long long)__float_as_uint(bv)) << 32) |
            (unsigned int)(~bi);

        // DPP wave-64 max reduce into lane 63
        {
            unsigned int lo, hi, slo, shi;
#define DSTEP(CTRL) \
            lo = (unsigned int)p; hi = (unsigned int)(p >> 32); \
            slo = __builtin_amdgcn_update_dpp(0, (int)lo, CTRL, 0xf, 0xf, true); \
            shi = __builtin_amdgcn_update_dpp(0, (int)hi, CTRL, 0xf, 0xf, true); \
            p = dpp_max_step(p, slo, shi);
            DSTEP(0x111)  // row_shr:1
            DSTEP(0x112)  // row_shr:2
            DSTEP(0x114)  // row_shr:4
            DSTEP(0x118)  // row_shr:8
            DSTEP(0x142)  // row_bcast:15
            DSTEP(0x143)  // row_bcast:31
#undef DSTEP
        }

        int par = t & 1;
        if ((tid & 63) == 63) pwv[par][tid >> 6] = p;
        __syncthreads();

        unsigned long long c0 = pwv[par][0];
        unsigned long long c1 = pwv[par][1];
        unsigned long long c2 = pwv[par][2];
        unsigned long long c3 = pwv[par][3];
        unsigned long long m01 = (c0 > c1) ? c0 : c1;
        unsigned long long m23 = (c2 > c3) ? c2 : c3;
        unsigned long long mm  = (m01 > m23) ? m01 : m23;
        cur = (int)(~(unsigned int)(mm & 0xffffffffULL));
    }
    __syncthreads();

    // epilogue: write selections in parallel, coalesced
    for (int t = tid; t < KSEL; t += 256) {
        int c = sel[t];
        int g = b * NPTS + c;
        int m = b * KSEL + t;
        fp_int[m] = g;
        inv[g] = m;
        out_fp[m] = (float)g;
        out_subx[m * 3 + 0] = sx[c];
        out_subx[m * 3 + 1] = sy[c];
        out_subx[m * 3 + 2] = sz[c];
    }
}

// ---------------- in-degree histogram + inv init --------------------------
// Runs (and completes) BEFORE fps: inv init here is race-free.
__global__ void deg_kernel(const int* __restrict__ dst, int* __restrict__ deg,
                           int* __restrict__ inv)
{
    int e = blockIdx.x * blockDim.x + threadIdx.x;
    if (e < N_NODES) inv[e] = -1;
    if (e < N_EDGES) atomicAdd(&deg[dst[e]], 1);
}

// ---------------- exclusive scan over deg -> row_ptr (+ cursor copy) ------
__global__ void scan_kernel(const int* __restrict__ deg, int* __restrict__ row_ptr,
                            int* __restrict__ row_ptr2)
{
    __shared__ int part[1024];
    int tid = threadIdx.x;
    int base = tid * 16;
    int local[16];
    int s = 0;
#pragma unroll
    for (int j = 0; j < 16; ++j) { local[j] = s; s += deg[base + j]; }
    part[tid] = s;
    __syncthreads();
    for (int off = 1; off < 1024; off <<= 1) {
        int v = part[tid];
        int add = (tid >= off) ? part[tid - off] : 0;
        __syncthreads();
        part[tid] = v + add;
        __syncthreads();
    }
    int prefix = (tid == 0) ? 0 : part[tid - 1];
#pragma unroll
    for (int j = 0; j < 16; ++j) {
        int v = prefix + local[j];
        row_ptr[base + j]  = v;
        row_ptr2[base + j] = v;   // consumed (destroyed) by scatter as cursor
    }
    if (tid == 1023) row_ptr[N_NODES] = part[1023];
}

// ---------------- CSR scatter (row_ptr2 doubles as cursor) ----------------
__global__ void scatter_kernel(const int* __restrict__ src, const int* __restrict__ dst,
                               int* __restrict__ row_ptr2, int* __restrict__ col)
{
    int e = blockIdx.x * blockDim.x + threadIdx.x;
    if (e < N_EDGES) {
        int r = atomicAdd(&row_ptr2[dst[e]], 1);  // returns absolute slot
        col[r] = src[e];
    }
}

// ---------------- fused agg (blocks 0..2047) + edge (blocks 2048..4095) ---
__global__ void agg_edge_kernel(const float* __restrict__ feat,
                                const int* __restrict__ fp_int,
                                const int* __restrict__ row_ptr,
                                const int* __restrict__ col,
                                const int* __restrict__ deg,
                                float* __restrict__ out_subfeat,
                                const int* __restrict__ src,
                                const int* __restrict__ dst,
                                const int* __restrict__ inv,
                                const float* __restrict__ subx,
                                float* __restrict__ outd,
                                float* __restrict__ outw,
                                float* __restrict__ outm)
{
    if (blockIdx.x < 2048) {
        // mean aggregation: one wave per sampled node, lane = 2 feature cols.
        // x2 unroll, independent accumulators (two load streams in flight).
        int wid  = (blockIdx.x * blockDim.x + threadIdx.x) >> 6;
        int lane = threadIdx.x & 63;
        int v  = fp_int[wid];
        int s0 = row_ptr[v];
        int s1 = row_ptr[v + 1];
        float a0 = 0.0f, a1 = 0.0f, b0 = 0.0f, b1 = 0.0f;
        int e = s0;
        for (; e + 1 < s1; e += 2) {
            int sA = col[e];
            int sB = col[e + 1];
            float2 vA = ((const float2*)(feat + (size_t)sA * D_FEAT))[lane];
            float2 vB = ((const float2*)(feat + (size_t)sB * D_FEAT))[lane];
            a0 += vA.x; a1 += vA.y;
            b0 += vB.x; b1 += vB.y;
        }
        if (e < s1) {
            int sA = col[e];
            float2 vA = ((const float2*)(feat + (size_t)sA * D_FEAT))[lane];
            a0 += vA.x; a1 += vA.y;
        }
        a0 += b0; a1 += b1;
        float dv = fmaxf((float)deg[v], 1.0f);
        float* o = out_subfeat + (size_t)wid * D_FEAT + lane * 2;
        o[0] = a0 / dv;
        o[1] = a1 / dv;
    } else {
        int e = (blockIdx.x - 2048) * blockDim.x + threadIdx.x;
        int ls = inv[src[e]];
        int ld = inv[dst[e]];
        bool mk = (ls >= 0) && (ld >= 0);
        float dx = 0.0f, dy = 0.0f, dz = 0.0f;
        if (mk) {
            dx = __fsub_rn(subx[ld * 3 + 0], subx[ls * 3 + 0]);
            dy = __fsub_rn(subx[ld * 3 + 1], subx[ls * 3 + 1]);
            dz = __fsub_rn(subx[ld * 3 + 2], subx[ls * 3 + 2]);
        }
        float w = sqrtf(__fadd_rn(__fadd_rn(__fmul_rn(dx, dx), __fmul_rn(dy, dy)),
                                  __fmul_rn(dz, dz)));
        outd[e * 3 + 0] = dx;
        outd[e * 3 + 1] = dy;
        outd[e * 3 + 2] = dz;
        outw[e] = w;
        outm[e] = mk ? 1.0f : 0.0f;
    }
}

// ---------------- launch ---------------------------------------------------
extern "C" void kernel_launch(void* const* d_in, const int* in_sizes, int n_in,
                              void* d_out, int out_size, void* d_ws, size_t ws_size,
                              hipStream_t stream)
{
    const float* pos  = (const float*)d_in[0];   // [16384,3]
    const float* feat = (const float*)d_in[1];   // [16384,128]
    const int*   src  = (const int*)d_in[2];     // [524288]
    const int*   dst  = (const int*)d_in[3];     // [524288]

    float* out = (float*)d_out;
    float* out_subx    = out;                                 // [8192,3]
    float* out_subfeat = out_subx + (size_t)MSEL * 3;         // [8192,128]
    float* out_d       = out_subfeat + (size_t)MSEL * D_FEAT; // [524288,3]
    float* out_w       = out_d + (size_t)N_EDGES * 3;         // [524288]
    float* out_m       = out_w + (size_t)N_EDGES;             // [524288]
    float* out_fp      = out_m + (size_t)N_EDGES;             // [8192]

    int* fp_int   = (int*)d_ws;               // 8192
    int* inv      = fp_int + MSEL;            // 16384
    int* deg      = inv + N_NODES;            // 16384
    int* row_ptr  = deg + N_NODES;            // 16385
    int* row_ptr2 = row_ptr + (N_NODES + 1);  // 16385
    int* col      = row_ptr2 + (N_NODES + 1); // 524288

    (void)hipMemsetAsync(deg, 0, (size_t)N_NODES * 4, stream);

    deg_kernel<<<N_EDGES / 256, 256, 0, stream>>>(dst, deg, inv);
    scan_kernel<<<1, 1024, 0, stream>>>(deg, row_ptr, row_ptr2);
    scatter_kernel<<<N_EDGES / 256, 256, 0, stream>>>(src, dst, row_ptr2, col);

    fps_kernel<<<BATCH, 256, 0, stream>>>(pos, fp_int, inv, out_subx, out_fp);

    agg_edge_kernel<<<4096, 256, 0, stream>>>(feat, fp_int, row_ptr, col, deg,
                                              out_subfeat, src, dst, inv, out_subx,
                                              out_d, out_w, out_m);
}